// Round 6
// baseline (122.780 us; speedup 1.0000x reference)
//
#include <hip/hip_runtime.h>
#include <hip/hip_fp16.h>

#define N 224        // image size
#define M 32         // CUT (number of sine modes)
#define NPIX (N * N) // 50176
#define NPLANE 384   // 128 * 3
#define RB 1024      // remap block threads (16 waves)
#define PXW (NPIX / (RB / 64))  // pixels per wave = 3136
#define ITERS (PXW / 64)        // 49
#define PI_F 3.14159265358979323846f

typedef float vfloat4 __attribute__((ext_vector_type(4)));

// ---------------- Stage 1: displacement field -> bilinear table ------------
// tab[pix] = (base = by*N+bx, fx, fy, 0), canonical form (identical to the
// reference's floor/ceil form in all cases incl. integer and clamped coords).
__global__ __launch_bounds__(256) void field_kernel(
    const float* __restrict__ Fx, const float* __restrict__ Fy,
    int4* __restrict__ tab)
{
    __shared__ float cx[M][M];
    __shared__ float cy[M][M];
    __shared__ float sy[M];

    const int t = threadIdx.x;
    const int y = blockIdx.x;

    for (int idx = t; idx < M * M; idx += 256) {
        const int i = idx / M, j = idx % M;
        const float fi = (float)(i + 1), fj = (float)(j + 1);
        const float r = sqrtf(fi * fi + fj * fj);
        const float e = (r < (float)M + 0.5f) ? (1.0f / r) : 0.0f;
        cx[i][j] = Fx[idx] * e;
        cy[i][j] = Fy[idx] * e;
    }
    if (t < M) {
        const float ys = (float)y / (float)(N - 1);
        sy[t] = sinf(PI_F * ys * (float)(t + 1));
    }
    __syncthreads();

    if (t >= N) return;
    const int x = t;

    float sx[M];
    const float xsv = (float)x / (float)(N - 1);
#pragma unroll
    for (int i = 0; i < M; ++i)
        sx[i] = sinf(PI_F * xsv * (float)(i + 1));

    float u = 0.0f, v = 0.0f;
#pragma unroll 1
    for (int j = 0; j < M; ++j) {
        float tx = 0.0f, ty = 0.0f;
#pragma unroll
        for (int i = 0; i < M; ++i) {
            tx = fmaf(cx[i][j], sx[i], tx);
            ty = fmaf(cy[i][j], sx[i], ty);
        }
        const float syj = sy[j];
        u = fmaf(syj, tx, u);
        v = fmaf(syj, ty, v);
    }

    const float dxv = 22.4f * u;   // sqrt(T)*n = 0.1*224
    const float dyv = 22.4f * v;
    const float xn = fminf(fmaxf((float)x + dxv, 0.0f), (float)(N - 1));
    const float yn = fminf(fmaxf((float)y + dyv, 0.0f), (float)(N - 1));
    const int bx = min((int)floorf(xn), N - 2);
    const int by = min((int)floorf(yn), N - 2);
    const float fx = xn - (float)bx;
    const float fy = yn - (float)by;

    tab[y * N + x] = make_int4(by * N + bx,
                               __float_as_int(fx), __float_as_int(fy), 0);
}

// -------- Stage 2: one block per plane; whole plane staged in LDS fp16 -----
// Stage-in: coalesced float4 (nontemporal: each byte read exactly once),
// converted to fp16, 98 KB LDS. Gather: 4 x ds_read_u16 per output pixel.
// A wave handles 64 consecutive x of one row -> near-lane-linear LDS
// addresses -> ~conflict-free. Stores coalesced + nontemporal.
__global__ __launch_bounds__(RB) void remap_kernel(
    const float* __restrict__ x, const int4* __restrict__ tab,
    float* __restrict__ out)
{
    __shared__ __half pl[NPIX];   // 100,352 B

    const int tid = threadIdx.x;
    const int plane = blockIdx.x;
    const float* img = x + (size_t)plane * NPIX;

    // ---- stage-in: f32 -> f16 LDS (50176 floats = 12544 float4) ----
    const vfloat4* src = (const vfloat4*)img;
    __half2* dst = (__half2*)pl;
    for (int i = tid; i < NPIX / 4; i += RB) {
        const vfloat4 v = __builtin_nontemporal_load(src + i);
        dst[2 * i]     = __floats2half2_rn(v.x, v.y);
        dst[2 * i + 1] = __floats2half2_rn(v.z, v.w);
    }
    __syncthreads();

    // ---- gather: wave w owns pixels [w*3136, (w+1)*3136) ----
    const int w = tid >> 6, l = tid & 63;
    float* ob = out + (size_t)plane * NPIX;
    int px = w * PXW + l;

#pragma unroll 7
    for (int k = 0; k < ITERS; ++k, px += 64) {
        const int4 tb = tab[px];
        const int b = tb.x;
        const float fx = __int_as_float(tb.y);
        const float fy = __int_as_float(tb.z);
        const float omx = 1.0f - fx, omy = 1.0f - fy;

        const float v00 = __half2float(pl[b]);
        const float v01 = __half2float(pl[b + 1]);
        const float v10 = __half2float(pl[b + N]);
        const float v11 = __half2float(pl[b + N + 1]);

        const float val = omy * (omx * v00 + fx * v01)
                        + fy  * (omx * v10 + fx * v11);
        __builtin_nontemporal_store(val, ob + px);
    }
}

extern "C" void kernel_launch(void* const* d_in, const int* in_sizes, int n_in,
                              void* d_out, int out_size, void* d_ws, size_t ws_size,
                              hipStream_t stream) {
    const float* x  = (const float*)d_in[0];   // [128,3,224,224]
    const float* Fx = (const float*)d_in[1];   // [32,32]
    const float* Fy = (const float*)d_in[2];   // [32,32]
    float* out = (float*)d_out;

    int4* tab = (int4*)d_ws;                   // 802,816 B

    field_kernel<<<N, 256, 0, stream>>>(Fx, Fy, tab);
    remap_kernel<<<NPLANE, RB, 0, stream>>>(x, tab, out);
}

// Round 8
// 63.448 us; speedup vs baseline: 1.9351x; 1.9351x over previous
//
#include <hip/hip_runtime.h>
#include <hip/hip_fp16.h>

#define N 224        // image size
#define M 32         // CUT (number of sine modes)
#define NPIX (N * N) // 50176
#define NPLANE 384   // 128 * 3
#define PLT 128      // planes per group
#define NPGRP 3      // 384 / 128
#define TPX 128      // transpose pixel tile
#define NTTILE (NPIX / TPX)   // 392
#define RPX 64       // remap pixel tile
#define NCHUNK (NPIX / RPX)   // 784
#define NXCD 8
#define CPX (NCHUNK / NXCD)   // 98
#define PI_F 3.14159265358979323846f

typedef float vfloat4 __attribute__((ext_vector_type(4)));
typedef float vfloat2 __attribute__((ext_vector_type(2)));

// ---------------- Stage 1: displacement field -> bilinear table ------------
// tab[pix] = (base = by*N+bx, fx, fy, 0), canonical form (identical to the
// reference's floor/ceil form in all cases incl. integer and clamped coords).
__global__ __launch_bounds__(256) void field_kernel(
    const float* __restrict__ Fx, const float* __restrict__ Fy,
    int4* __restrict__ tab)
{
    __shared__ float cx[M][M];
    __shared__ float cy[M][M];
    __shared__ float sy[M];

    const int t = threadIdx.x;
    const int y = blockIdx.x;

    for (int idx = t; idx < M * M; idx += 256) {
        const int i = idx / M, j = idx % M;
        const float fi = (float)(i + 1), fj = (float)(j + 1);
        const float r = sqrtf(fi * fi + fj * fj);
        const float e = (r < (float)M + 0.5f) ? (1.0f / r) : 0.0f;
        cx[i][j] = Fx[idx] * e;
        cy[i][j] = Fy[idx] * e;
    }
    if (t < M) {
        const float ys = (float)y / (float)(N - 1);
        sy[t] = sinf(PI_F * ys * (float)(t + 1));
    }
    __syncthreads();

    if (t >= N) return;
    const int x = t;

    float sx[M];
    const float xsv = (float)x / (float)(N - 1);
#pragma unroll
    for (int i = 0; i < M; ++i)
        sx[i] = sinf(PI_F * xsv * (float)(i + 1));

    float u = 0.0f, v = 0.0f;
#pragma unroll 1
    for (int j = 0; j < M; ++j) {
        float tx = 0.0f, ty = 0.0f;
#pragma unroll
        for (int i = 0; i < M; ++i) {
            tx = fmaf(cx[i][j], sx[i], tx);
            ty = fmaf(cy[i][j], sx[i], ty);
        }
        const float syj = sy[j];
        u = fmaf(syj, tx, u);
        v = fmaf(syj, ty, v);
    }

    const float dxv = 22.4f * u;   // sqrt(T)*n = 0.1*224
    const float dyv = 22.4f * v;
    const float xn = fminf(fmaxf((float)x + dxv, 0.0f), (float)(N - 1));
    const float yn = fminf(fmaxf((float)y + dyv, 0.0f), (float)(N - 1));
    const int bx = min((int)floorf(xn), N - 2);
    const int by = min((int)floorf(yn), N - 2);
    const float fx = xn - (float)bx;
    const float fy = yn - (float)by;

    tab[y * N + x] = make_int4(by * N + bx,
                               __float_as_int(fx), __float_as_int(fy), 0);
}

// --- Stage 2: transpose x[384][50176] f32 -> xt[3][50176][128] fp16 --------
// Block (pg, tile): planes [pg*128,+128) x pixels [tile*128,+128).
// Load: float4/lane, half-wave per plane-row (2x512B segments per inst).
// LDS tile [plane][pixel+pad]. Store: uint2/lane (4 planes), half-wave per
// pixel -> 512 B contiguous per inst.
__global__ __launch_bounds__(256) void transpose_kernel(
    const float* __restrict__ x, __half* __restrict__ xt)
{
    __shared__ __half t[PLT][130];   // pad 130: writes 2-way (free), reads 4-way

    const int tid = threadIdx.x;
    const int w = tid >> 6, l = tid & 63;
    const int m = l & 31, h = l >> 5;
    const int pg   = blockIdx.x / NTTILE;
    const int tile = blockIdx.x % NTTILE;
    const int pix0 = tile * TPX;
    const int plane0 = pg * PLT;

#pragma unroll
    for (int i = 0; i < 16; ++i) {
        const int p = 2 * (w * 16 + i) + h;   // local plane 0..127
        const vfloat4 v = *(const vfloat4*)(
            x + (size_t)(plane0 + p) * NPIX + pix0 + 4 * m);
        *(__half2*)&t[p][4 * m]     = __floats2half2_rn(v.x, v.y);
        *(__half2*)&t[p][4 * m + 2] = __floats2half2_rn(v.z, v.w);
    }
    __syncthreads();

    __half* xo = xt + ((size_t)pg * NPIX + pix0) * PLT;
#pragma unroll
    for (int s = 0; s < 16; ++s) {
        const int P = 2 * (w * 16 + s) + h;   // local pixel 0..127
        const __half2 h0 = __halves2half2(t[4 * m][P],     t[4 * m + 1][P]);
        const __half2 h1 = __halves2half2(t[4 * m + 2][P], t[4 * m + 3][P]);
        union { uint2 u; __half2 hh[2]; } pk;
        pk.hh[0] = h0; pk.hh[1] = h1;
        *(uint2*)&xo[(size_t)P * PLT + 4 * m] = pk.u;   // 8B/lane, 512B/inst
    }
}

// --- Stage 3: remap, planes-in-lanes (all VMEM coalesced) ------------------
// Block = 64 pixels x 128 planes (one pgrp). Gather: per pixel, 4 coalesced
// half2 loads (lane = plane-pair; pixel slice = 256 B, x-corners adjacent).
// LDS tile re-transposes; stores vfloat2/lane nontemporal (2x256B segs/inst).
// Grid XCD-clustered: xcd owns pixel chunks [xcd*98,(xcd+1)*98) of each pgrp.
__global__ __launch_bounds__(256) void remap_kernel(
    const __half* __restrict__ xt, const int4* __restrict__ tab,
    float* __restrict__ out)
{
    __shared__ float tile[RPX][130];  // writes 2-way (free), reads 4-way
    __shared__ int4 ltab[RPX];

    const int tid = threadIdx.x;
    const int w = tid >> 6, l = tid & 63;

    const int bid   = blockIdx.x;
    const int xcd   = bid & 7;
    const int local = bid >> 3;          // 0..293
    const int pg    = local / CPX;       // 0..2
    const int chunk = xcd * CPX + (local % CPX);
    const int pix0  = chunk * RPX;

    if (tid < RPX) ltab[tid] = tab[pix0 + tid];
    __syncthreads();

    const __half2* base = (const __half2*)(xt + (size_t)pg * NPIX * PLT);

#pragma unroll 8
    for (int i = 0; i < 16; ++i) {
        const int pl = w * 16 + i;       // pixel-local index
        const int4 tb = ltab[pl];
        const float fx = __int_as_float(tb.y);
        const float fy = __int_as_float(tb.z);
        const float omx = 1.0f - fx, omy = 1.0f - fy;
        const float w00 = omy * omx, w01 = omy * fx;
        const float w10 = fy * omx,  w11 = fy * fx;

        const size_t b0 = (size_t)tb.x * (PLT / 2);   // half2 units
        const float2 c00 = __half22float2(base[b0 + l]);                  // (by,  bx)
        const float2 c01 = __half22float2(base[b0 + PLT / 2 + l]);        // (by,  bx+1)
        const float2 c10 = __half22float2(base[b0 + (size_t)N * (PLT/2) + l]);           // (by+1,bx)
        const float2 c11 = __half22float2(base[b0 + (size_t)N * (PLT/2) + PLT/2 + l]);   // (by+1,bx+1)

        float2 o;
        o.x = w00 * c00.x + w01 * c01.x + w10 * c10.x + w11 * c11.x;
        o.y = w00 * c00.y + w01 * c01.y + w10 * c10.y + w11 * c11.y;
        *(float2*)&tile[pl][2 * l] = o;  // planes (2l,2l+1) of pixel pl
    }
    __syncthreads();

    const int l2 = tid & 31, jg = tid >> 5;   // pixel-pair, plane-group
    float* ob = out + (size_t)pg * PLT * NPIX + pix0;
#pragma unroll
    for (int s = 0; s < 16; ++s) {
        const int j = jg * 16 + s;            // plane 0..127
        vfloat2 o2;
        o2.x = tile[2 * l2][j];
        o2.y = tile[2 * l2 + 1][j];
        __builtin_nontemporal_store(o2, (vfloat2*)&ob[(size_t)j * NPIX + 2 * l2]);
    }
}

extern "C" void kernel_launch(void* const* d_in, const int* in_sizes, int n_in,
                              void* d_out, int out_size, void* d_ws, size_t ws_size,
                              hipStream_t stream) {
    const float* x  = (const float*)d_in[0];   // [128,3,224,224]
    const float* Fx = (const float*)d_in[1];   // [32,32]
    const float* Fy = (const float*)d_in[2];   // [32,32]
    float* out = (float*)d_out;

    int4* tab = (int4*)d_ws;                               // 802,816 B
    const size_t tab_bytes = (size_t)NPIX * sizeof(int4);
    __half* xt = (__half*)((char*)d_ws + tab_bytes);       // 38.5 MB

    field_kernel<<<N, 256, 0, stream>>>(Fx, Fy, tab);
    transpose_kernel<<<NPGRP * NTTILE, 256, 0, stream>>>(x, xt);
    remap_kernel<<<NCHUNK * NPGRP, 256, 0, stream>>>(xt, tab, out);
}